// Round 1
// baseline (4649.073 us; speedup 1.0000x reference)
//
#include <hip/hip_runtime.h>
#include <cstdint>
#include <cstddef>

// Problem dims (fixed)
#define B_    512
#define TM1_  255
#define D_    128
#define H_    1024
#define FOURH 4096
#define KTOT  1152   // D_ + H_ : concatenated K for [w_t | h] @ [W_ih | W_hh]^T

typedef __bf16 bf16;
typedef __bf16 bf16x8 __attribute__((ext_vector_type(8)));
typedef float  f32x4  __attribute__((ext_vector_type(4)));

// ---- async global->LDS, 16B per lane; LDS dest must be wave-uniform base ----
__device__ __forceinline__ void async16(void* lds, const void* g) {
  __builtin_amdgcn_global_load_lds(
      (const __attribute__((address_space(1))) void*)g,
      (__attribute__((address_space(3))) void*)lds, 16, 0, 0);
}

__device__ __forceinline__ float sigm(float x)   { return 1.f / (1.f + __expf(-x)); }
// NaN-safe tanh: 1 - 2/(e^{2x}+1)  (inf -> 1, 0 -> -1)
__device__ __forceinline__ float tanh_f(float x) { return 1.f - 2.f / (__expf(2.f * x) + 1.f); }

// ---------------------------------------------------------------------------
// prep: Wcat[n][k] bf16, k<128 -> W_ih[n][k], else W_hh[n][k-128]
// ---------------------------------------------------------------------------
__global__ void prep_w(const float* __restrict__ W_ih, const float* __restrict__ W_hh,
                       bf16* __restrict__ Wcat) {
  int i = blockIdx.x * 256 + threadIdx.x;           // 0 .. 4096*1152-1 (exact grid)
  int n = i / KTOT;
  int k = i - n * KTOT;
  float v = (k < D_) ? W_ih[n * D_ + k] : W_hh[(size_t)n * H_ + (k - D_)];
  Wcat[i] = (bf16)v;
}

__global__ void prep_b(const float* __restrict__ b_ih, const float* __restrict__ b_hh,
                       float* __restrict__ bsum) {
  int i = blockIdx.x * 256 + threadIdx.x;
  if (i < FOURH) bsum[i] = b_ih[i] + b_hh[i];
}

// ---------------------------------------------------------------------------
// attention: per batch row b compute e_x[d] = sum_t x[b,t,d]*wx[t], softmax over d,
// write out0[b,t,d] = a[d]*x[b,t,d] (fp32) and wbf[t][b][d] (bf16)
// ---------------------------------------------------------------------------
__global__ void attn_kernel(const float* __restrict__ x, const float* __restrict__ W_attn,
                            float* __restrict__ out0, bf16* __restrict__ wbf) {
  const int b    = blockIdx.x;
  const int tid  = threadIdx.x;      // 256
  const int d    = tid & 127;
  const int half = tid >> 7;

  __shared__ float e2[2][D_];
  __shared__ float a_sh[D_];
  __shared__ float red_sh[2];

  const float* xb = x + (size_t)b * TM1_ * D_;
  const float* wx = W_attn + 2 * H_;             // wx[t] = W_attn[0, 2H + t]

  float acc = 0.f;
  for (int t = half; t < TM1_; t += 2) acc += xb[(size_t)t * D_ + d] * wx[t];
  e2[half][d] = acc;
  __syncthreads();

  if (tid < D_) { a_sh[tid] = e2[0][tid] + e2[1][tid]; }
  __syncthreads();
  if (tid < 64) {
    float m = fmaxf(a_sh[tid], a_sh[tid + 64]);
    for (int o = 32; o; o >>= 1) m = fmaxf(m, __shfl_xor(m, o, 64));
    if (tid == 0) red_sh[0] = m;
  }
  __syncthreads();
  float mx = red_sh[0];
  if (tid < D_) a_sh[tid] = __expf(a_sh[tid] - mx);
  __syncthreads();
  if (tid < 64) {
    float s = a_sh[tid] + a_sh[tid + 64];
    for (int o = 32; o; o >>= 1) s += __shfl_xor(s, o, 64);
    if (tid == 0) red_sh[1] = s;
  }
  __syncthreads();
  float inv = 1.f / red_sh[1];
  if (tid < D_) a_sh[tid] *= inv;
  __syncthreads();

  const float a = a_sh[d];
  for (int t0 = 0; t0 < TM1_ - 1; t0 += 2) {   // 254 even, +1 tail
    int t = t0 + half;
    float w = a * xb[(size_t)t * D_ + d];
    out0[((size_t)b * TM1_ + t) * D_ + d] = w;
    wbf[((size_t)t * B_ + b) * D_ + d]    = (bf16)w;
  }
  if (half == 0) {  // t = 254 tail
    int t = TM1_ - 1;
    float w = a * xb[(size_t)t * D_ + d];
    out0[((size_t)b * TM1_ + t) * D_ + d] = w;
    wbf[((size_t)t * B_ + b) * D_ + d]    = (bf16)w;
  }
}

// ---------------------------------------------------------------------------
// step kernel: one LSTM timestep.
// grid 256 (1/CU), block 512 (8 waves).
// Block tile: M=64 batch rows x 128 gate cols (4 gates x 32 hidden cols) with
// K = 1152 = [w_t (128) | h (1024)].
// bid&7 = XCD -> hidden-col group of 128 (L2 locality); idx=bid>>3:
//   m_tile = idx&7 (64 rows), sub_k = idx>>3 (which 32-col tile in the group).
// LDS: A[2][64][64] bf16 @0 (16KB), B[2][128][64] bf16 @16KB (32KB).
// XOR swizzle on 16B chunks within the 128B row: chunk' = chunk ^ (row&7);
// dest stays linear for global_load_lds, the source address is pre-swizzled.
// ---------------------------------------------------------------------------
__global__ __launch_bounds__(512) void step_kernel(
    const bf16* __restrict__ wbf,    // [TM1][B][D]
    const bf16* __restrict__ Wcat,   // [4096][1152]
    const float* __restrict__ bsum,  // [4096]
    const bf16* __restrict__ h_cur,  // [B][H]
    bf16* __restrict__ h_next,       // [B][H]
    float* __restrict__ c_ws,        // [B][H] fp32
    float* __restrict__ out1,        // d_out + B*TM1*D, layout [b][t][H]
    int t)
{
  __shared__ __align__(16) uint8_t smem[49152];

  const int tid  = threadIdx.x;
  const int lane = tid & 63;
  const int wid  = tid >> 6;

  const int bid    = blockIdx.x;
  const int xcd    = bid & 7;
  const int idx    = bid >> 3;
  const int m_tile = idx & 7;
  const int sub_k  = idx >> 3;
  const int brow   = m_tile * 64;
  const int kt     = xcd * 4 + sub_k;       // hidden tile 0..31
  const int hcol0  = kt * 32;

  // ---- staging thread mapping (per wave: A 8 rows, B 16 rows = 2 calls) ----
  const int ra  = wid * 8 + (lane >> 3);             // A row 0..63
  const int ca  = (lane & 7) ^ (ra & 7);             // pre-swizzled 16B chunk
  const int rb0 = wid * 16 + (lane >> 3);            // B rows
  const int rb1 = rb0 + 8;
  const int cb0 = (lane & 7) ^ (rb0 & 7);
  const int cb1 = (lane & 7) ^ (rb1 & 7);
  const int nb0 = (rb0 >> 5) * H_ + hcol0 + (rb0 & 31);   // global Wcat row
  const int nb1 = (rb1 >> 5) * H_ + hcol0 + (rb1 & 31);

  const bf16* wrowA = wbf + ((size_t)t * B_ + brow + ra) * D_;
  const bf16* hrowA = h_cur + (size_t)(brow + ra) * H_;
  const bf16* wrB0  = Wcat + (size_t)nb0 * KTOT;
  const bf16* wrB1  = Wcat + (size_t)nb1 * KTOT;

  uint8_t* ldsA_w = smem + wid * 1024;                 // + buf*8192
  uint8_t* ldsB_w = smem + 16384 + wid * 2048;         // + buf*16384

#define STAGE(bufi, k0)                                                        \
  {                                                                            \
    const bf16* srcA = ((k0) < D_) ? (wrowA + (k0) + ca * 8)                   \
                                   : (hrowA + ((k0) - D_) + ca * 8);           \
    async16(ldsA_w + (bufi) * 8192, srcA);                                     \
    async16(ldsB_w + (bufi) * 16384, wrB0 + (k0) + cb0 * 8);                   \
    async16(ldsB_w + (bufi) * 16384 + 1024, wrB1 + (k0) + cb1 * 8);            \
  }

  // ---- MFMA fragment indexing ----
  const int wave_m = wid >> 2;   // 0..1
  const int wave_n = wid & 3;    // 0..3
  const int arow   = wave_m * 32 + (lane & 15);
  const int brow_f = wave_n * 32 + (lane & 15);
  const int kg     = lane >> 4;  // 0..3
  const int axor   = arow & 7;
  const int bxor   = brow_f & 7;

  f32x4 acc[2][2] = {};

  STAGE(0, 0);
  const int NS = KTOT / 64;   // 18
  for (int s = 0; s < NS; ++s) {
    const int buf = s & 1;
    if (s + 1 < NS) {
      STAGE(buf ^ 1, (s + 1) * 64);
      asm volatile("s_waitcnt vmcnt(3)" ::: "memory");
    } else {
      asm volatile("s_waitcnt vmcnt(0)" ::: "memory");
    }
    __syncthreads();

    const uint8_t* Ab = smem + buf * 8192;
    const uint8_t* Bb = smem + 16384 + buf * 16384;
#pragma unroll
    for (int ko = 0; ko < 2; ++ko) {
      const int kc = ko * 4 + kg;
      bf16x8 a0 = *(const bf16x8*)(Ab + (arow)      * 128 + ((kc ^ axor) << 4));
      bf16x8 a1 = *(const bf16x8*)(Ab + (arow + 16) * 128 + ((kc ^ axor) << 4));
      bf16x8 b0 = *(const bf16x8*)(Bb + (brow_f)      * 128 + ((kc ^ bxor) << 4));
      bf16x8 b1 = *(const bf16x8*)(Bb + (brow_f + 16) * 128 + ((kc ^ bxor) << 4));
      acc[0][0] = __builtin_amdgcn_mfma_f32_16x16x32_bf16(a0, b0, acc[0][0], 0, 0, 0);
      acc[0][1] = __builtin_amdgcn_mfma_f32_16x16x32_bf16(a0, b1, acc[0][1], 0, 0, 0);
      acc[1][0] = __builtin_amdgcn_mfma_f32_16x16x32_bf16(a1, b0, acc[1][0], 0, 0, 0);
      acc[1][1] = __builtin_amdgcn_mfma_f32_16x16x32_bf16(a1, b1, acc[1][1], 0, 0, 0);
    }
    __syncthreads();
  }
#undef STAGE

  // ---- write gates to LDS (reuse staging area), padded stride 132 ----
  float* gl = (float*)smem;   // [64][132]
#pragma unroll
  for (int mf = 0; mf < 2; ++mf)
#pragma unroll
    for (int nf = 0; nf < 2; ++nf)
#pragma unroll
      for (int r = 0; r < 4; ++r) {
        int row = wave_m * 32 + mf * 16 + kg * 4 + r;
        int col = wave_n * 32 + nf * 16 + (lane & 15);
        gl[row * 132 + col] = acc[mf][nf][r];
      }
  __syncthreads();

  // ---- LSTM elementwise: 64 rows x 32 hidden cols = 2048 = 512 thr x 4 ----
#pragma unroll
  for (int p = 0; p < 4; ++p) {
    int i2  = p * 512 + tid;
    int row = i2 >> 5;
    int jj  = i2 & 31;
    float gi = gl[row * 132 +      jj] + bsum[0 * H_ + hcol0 + jj];
    float gf = gl[row * 132 + 32 + jj] + bsum[1 * H_ + hcol0 + jj];
    float gg = gl[row * 132 + 64 + jj] + bsum[2 * H_ + hcol0 + jj];
    float go = gl[row * 132 + 96 + jj] + bsum[3 * H_ + hcol0 + jj];
    size_t ci = (size_t)(brow + row) * H_ + hcol0 + jj;
    float c_old = c_ws[ci];
    float cn = sigm(gf) * c_old + sigm(gi) * tanh_f(gg);
    float hn = sigm(go) * tanh_f(cn);
    c_ws[ci]   = cn;
    h_next[ci] = (bf16)hn;
    out1[((size_t)(brow + row) * TM1_ + t) * H_ + hcol0 + jj] = hn;
  }
}

// ---------------------------------------------------------------------------
extern "C" void kernel_launch(void* const* d_in, const int* in_sizes, int n_in,
                              void* d_out, int out_size, void* d_ws, size_t ws_size,
                              hipStream_t stream) {
  (void)in_sizes; (void)n_in; (void)out_size; (void)ws_size;
  const float* x      = (const float*)d_in[0];
  const float* W_attn = (const float*)d_in[1];
  // d_in[2] = b_attn: unused (softmax shift-invariance)
  const float* W_ih   = (const float*)d_in[3];
  const float* W_hh   = (const float*)d_in[4];
  const float* b_ih   = (const float*)d_in[5];
  const float* b_hh   = (const float*)d_in[6];
  float* out = (float*)d_out;

  char* ws = (char*)d_ws;
  bf16*  Wcat = (bf16*)(ws);                      // 4096*1152*2  = 9,437,184
  float* bsum = (float*)(ws + 9437184);           // 4096*4       = 16,384
  bf16*  wbf  = (bf16*)(ws + 9453568);            // 255*512*128*2= 33,423,360
  bf16*  hb0  = (bf16*)(ws + 42876928);           // 512*1024*2   = 1,048,576
  bf16*  hb1  = (bf16*)(ws + 43925504);           // 1,048,576
  float* cws  = (float*)(ws + 44974080);          // 512*1024*4   = 2,097,152

  hipMemsetAsync(hb0, 0, (size_t)B_ * H_ * sizeof(bf16), stream);
  hipMemsetAsync(cws, 0, (size_t)B_ * H_ * sizeof(float), stream);

  prep_w<<<(FOURH * KTOT) / 256, 256, 0, stream>>>(W_ih, W_hh, Wcat);
  prep_b<<<FOURH / 256, 256, 0, stream>>>(b_ih, b_hh, bsum);
  attn_kernel<<<B_, 256, 0, stream>>>(x, W_attn, out, wbf);

  float* out1 = out + (size_t)B_ * TM1_ * D_;
  for (int t = 0; t < TM1_; ++t) {
    bf16* hc = (t & 1) ? hb1 : hb0;
    bf16* hn = (t & 1) ? hb0 : hb1;
    step_kernel<<<256, 512, 0, stream>>>(wbf, Wcat, bsum, hc, hn, cws, out1, t);
  }
}